// Round 11
// baseline (193.094 us; speedup 1.0000x reference)
//
#include <hip/hip_runtime.h>
#include <hip/hip_bf16.h>

// RelationNet fused pipeline, fp32 in/out — FOUR dispatches, no grid barriers.
// B=4 Q=256 S=128 C=256; feats 512 -> 256 -> 64 -> 1; BN (training) + ReLU each layer.
//
// Factorization: concat(uq,us)@W0^T = query@W0a^T + support@W0b^T => Aq[b,q,o], As[b,s,o]
// (b0 folded into As). BN0 stats analytic from per-b sums:
//   sum  y0 = S*sum(Aq) + Q*sum(As)
//   sum y0^2 = S*sum(Aq^2) + Q*sum(As^2) + 2*sum_b (sum_q Aq[b])·(sum_s As[b])
// GEMM0 ~fp32 via 3-term hi/lo bf16 split (in-register). GEMM1: z-side bf16-RNE
// on the fly, W1-side hi/lo bf16 PRE-SPLIT to global in D1 (R10 regression undone:
// in-register W1 split cost ~80 VALU/ko in both main passes).
//
// R10 counters (k_m1/k_m2 = 44us each, MfmaUtil 7%, VALUBusy 22%, Occ 15.6%):
// latency-bound at 8 waves/CU. Fix: 1024 half-tile blocks (acc[2][4], lb(256,4))
// -> 4 blocks/CU = 16 waves/CU; XCD swizzle so each XCD's Aq/As set is ~256KB.

typedef __attribute__((ext_vector_type(4))) float f32x4;
typedef __attribute__((ext_vector_type(8))) short s16x8;

#define BN_EPS 1e-5f
#define INV_N  (1.0f/131072.0f)

__device__ __forceinline__ unsigned pk_bf16(float a, float b) {
  float2 t; t.x = a; t.y = b;
  __hip_bfloat162 h = __float22bfloat162_rn(t);
  return *reinterpret_cast<unsigned*>(&h);
}
__device__ __forceinline__ void split2(float a, float b, unsigned& uh, unsigned& ul) {
  uh = pk_bf16(a, b);
  float ha = __uint_as_float(uh << 16);
  float hb = __uint_as_float(uh & 0xFFFF0000u);
  ul = pk_bf16(a - ha, b - hb);
}

union frag_u { s16x8 v; unsigned u[4]; };

struct Args {
  const float *Sf, *Qf, *W0, *b0, *g0, *bt0, *W1, *b1, *g1, *bt1, *W2, *b2, *g2, *bt2;
  float *Aq, *As, *y2, *ws0s, *ws1f, *ws2f, *out;
  ushort *W1h, *W1l;
};

// ---------------------------------------------------------------------------
// D1: GEMM0. 97 blocks x 256 thr. Blocks 0..95: block bi = one 16-row chunk,
// wave w = one 16x64 tile. mtile<64: Aq; else As (+b0). W0 split in-register.
// BN0 partial slots (no atomics): ws0s[bi*512 + o] / [..+256+o] = sum/sumsq.
// Block 96: split W1 -> W1h/W1l (bf16) and zero ws1f/ws2f atomic pads.
// ---------------------------------------------------------------------------
__global__ __launch_bounds__(256) void k_g0(Args a)
{
  int bi = blockIdx.x, t = threadIdx.x;
  if (bi == 96) {
    // W1: 16384 elems, 64 per thread, split RNE-hi + residual-lo
    for (int k = 0; k < 32; k++) {
      int idx = t * 64 + k * 2;
      unsigned uh, ul;
      split2(a.W1[idx], a.W1[idx + 1], uh, ul);
      a.W1h[idx] = (ushort)(uh & 0xFFFFu); a.W1h[idx + 1] = (ushort)(uh >> 16);
      a.W1l[idx] = (ushort)(ul & 0xFFFFu); a.W1l[idx + 1] = (ushort)(ul >> 16);
    }
    for (int i = t; i < 2048; i += 256) a.ws1f[i] = 0.0f;
    if (t < 32) a.ws2f[t] = 0.0f;
    return;
  }
  int w = t >> 6, l = t & 63, l15 = l & 15, quad = l >> 4;
  bool isQ = (bi < 64);
  const float* X; float* Out; int m0, koff;
  if (isQ) { m0 = bi * 16; X = a.Qf; Out = a.Aq; koff = 0; }
  else     { m0 = (bi - 64) * 16; X = a.Sf; Out = a.As; koff = 256; }
  int n0 = w * 64;

  f32x4 acc[4] = {};
#pragma unroll
  for (int ko = 0; ko < 256; ko += 32) {
    const float* row = X + (m0 + l15) * 256 + ko + quad * 8;
    f32x4 v0 = *(const f32x4*)(row);
    f32x4 v1 = *(const f32x4*)(row + 4);
    frag_u ah, al;
#pragma unroll
    for (int j = 0; j < 2; j++) {
      split2(v0[2 * j], v0[2 * j + 1], ah.u[j], al.u[j]);
      split2(v1[2 * j], v1[2 * j + 1], ah.u[2 + j], al.u[2 + j]);
    }
#pragma unroll
    for (int nt = 0; nt < 4; nt++) {
      const float* wrow = a.W0 + (n0 + nt * 16 + l15) * 512 + koff + ko + quad * 8;
      f32x4 w0v = *(const f32x4*)(wrow);
      f32x4 w1v = *(const f32x4*)(wrow + 4);
      frag_u bh, bl;
      split2(w0v[0], w0v[1], bh.u[0], bl.u[0]);
      split2(w0v[2], w0v[3], bh.u[1], bl.u[1]);
      split2(w1v[0], w1v[1], bh.u[2], bl.u[2]);
      split2(w1v[2], w1v[3], bh.u[3], bl.u[3]);
      acc[nt] = __builtin_amdgcn_mfma_f32_16x16x32_bf16(ah.v, bh.v, acc[nt], 0, 0, 0);
      acc[nt] = __builtin_amdgcn_mfma_f32_16x16x32_bf16(al.v, bh.v, acc[nt], 0, 0, 0);
      acc[nt] = __builtin_amdgcn_mfma_f32_16x16x32_bf16(ah.v, bl.v, acc[nt], 0, 0, 0);
    }
  }
#pragma unroll
  for (int nt = 0; nt < 4; nt++) {
    int o = n0 + nt * 16 + l15;
    float bias = isQ ? 0.0f : a.b0[o];
    float cs = 0, cs2 = 0;
#pragma unroll
    for (int r = 0; r < 4; r++) {
      float y = acc[nt][r] + bias;
      Out[(m0 + quad * 4 + r) * 256 + o] = y;
      cs += y; cs2 += y * y;
    }
    cs  += __shfl_xor(cs, 16);  cs  += __shfl_xor(cs, 32);
    cs2 += __shfl_xor(cs2, 16); cs2 += __shfl_xor(cs2, 32);
    if (quad == 0) {
      a.ws0s[bi * 512 + o] = cs;
      a.ws0s[bi * 512 + 256 + o] = cs2;
    }
  }
}

// ---------------------------------------------------------------------------
// Tile mapping for the 1024-block main passes. XCD swizzle: x = bi&7 (XCD),
// r = bi>>3; G = x*16 + (r>>3) in [0,128): b = G>>5, qt = (G&31)>>1,
// half = G&1; st = r&7. Each XCD owns 1 b and 8 qt -> Aq 128KB + As 128KB
// working set, fully L2-resident.
// ---------------------------------------------------------------------------
__device__ __forceinline__ void tile_map(int bi, int& b, int& qt, int& half, int& st)
{
  int x = bi & 7, r = bi >> 3;
  int G = x * 16 + (r >> 3);
  b = G >> 5; int rem = G & 31; qt = rem >> 1; half = rem & 1;
  st = r & 7;
}

// Main-GEMM K-loop (layer-1), HALF tile: wave covers q rows qt*16+half*8+w*2+{0,1},
// s rows st*16+0..15, all 64 j. z0 in bf16-RNE A-frag layout in regs; W1 pre-split
// bf16 from global. D: col(lane&15)=j-in-tile, row(quad*4+r)=s-in-tile.
__device__ __forceinline__ void mfma_kloop(
    const float* __restrict__ Aq, const float* __restrict__ As,
    const float* sh_a0c0, const ushort* __restrict__ W1h,
    const ushort* __restrict__ W1l,
    int b, int qt, int half, int st, int w, int l15, int quad, f32x4 acc[2][4])
{
  const float* asrow = As + ((b << 7) + st * 16 + l15) * 256;
  const float* aqrow[2];
#pragma unroll
  for (int mt = 0; mt < 2; mt++)
    aqrow[mt] = Aq + ((b << 8) + qt * 16 + half * 8 + w * 2 + mt) * 256;

#pragma unroll
  for (int ko = 0; ko < 256; ko += 32) {
    int obase = ko + quad * 8;
    f32x4 a0v0 = *(const f32x4*)(sh_a0c0 + obase);
    f32x4 a0v1 = *(const f32x4*)(sh_a0c0 + obase + 4);
    f32x4 c0v0 = *(const f32x4*)(sh_a0c0 + 256 + obase);
    f32x4 c0v1 = *(const f32x4*)(sh_a0c0 + 256 + obase + 4);
    f32x4 as0 = *(const f32x4*)(asrow + obase);
    f32x4 as1 = *(const f32x4*)(asrow + obase + 4);

    s16x8 zh[2];
#pragma unroll
    for (int mt = 0; mt < 2; mt++) {
      f32x4 aq0 = *(const f32x4*)(aqrow[mt] + obase);
      f32x4 aq1 = *(const f32x4*)(aqrow[mt] + obase + 4);
      f32x4 z0 = (aq0 + as0) * a0v0 + c0v0;
      f32x4 z1 = (aq1 + as1) * a0v1 + c0v1;
      frag_u zz;
      zz.u[0] = pk_bf16(fmaxf(z0[0], 0.0f), fmaxf(z0[1], 0.0f));
      zz.u[1] = pk_bf16(fmaxf(z0[2], 0.0f), fmaxf(z0[3], 0.0f));
      zz.u[2] = pk_bf16(fmaxf(z1[0], 0.0f), fmaxf(z1[1], 0.0f));
      zz.u[3] = pk_bf16(fmaxf(z1[2], 0.0f), fmaxf(z1[3], 0.0f));
      zh[mt] = zz.v;
    }
#pragma unroll
    for (int nt = 0; nt < 4; nt++) {
      int off = (nt * 16 + l15) * 256 + obase;
      s16x8 bh = *(const s16x8*)(W1h + off);
      s16x8 bl = *(const s16x8*)(W1l + off);
#pragma unroll
      for (int mt = 0; mt < 2; mt++) {
        acc[mt][nt] = __builtin_amdgcn_mfma_f32_16x16x32_bf16(zh[mt], bh, acc[mt][nt], 0, 0, 0);
        acc[mt][nt] = __builtin_amdgcn_mfma_f32_16x16x32_bf16(zh[mt], bl, acc[mt][nt], 0, 0, 0);
      }
    }
  }
}

// Redundant per-block BN0 finalize from D1's slots -> LDS a0/c0.
__device__ __forceinline__ void bn0_finalize(const Args& a, int t, float* sh_a0c0)
{
  int o = t;
  float sumY = 0, cross = 0, SQ2 = 0, SS2 = 0;
#pragma unroll
  for (int b = 0; b < 4; b++) {
    float sq1 = 0, sq2 = 0, ss1 = 0, ss2 = 0;
#pragma unroll
    for (int c = 0; c < 16; c++) {
      sq1 += a.ws0s[(b * 16 + c) * 512 + o];
      sq2 += a.ws0s[(b * 16 + c) * 512 + 256 + o];
    }
#pragma unroll
    for (int c = 0; c < 8; c++) {
      ss1 += a.ws0s[(64 + b * 8 + c) * 512 + o];
      ss2 += a.ws0s[(64 + b * 8 + c) * 512 + 256 + o];
    }
    SQ2 += sq2; SS2 += ss2;
    sumY += 128.0f * sq1 + 256.0f * ss1;
    cross += sq1 * ss1;
  }
  float mean = sumY * INV_N;
  float var = (128.0f * SQ2 + 256.0f * SS2 + 2.0f * cross) * INV_N - mean * mean;
  float aa = a.g0[o] * rsqrtf(var + BN_EPS);
  sh_a0c0[o] = aa;
  sh_a0c0[256 + o] = a.bt0[o] - mean * aa;
}

// ---------------------------------------------------------------------------
// D2: main pass 1 — BN1 stats. 1024 half-tile blocks.
// BN1 partials -> 16-way-spread atomicAdd ws1f (64 adds/address).
// ---------------------------------------------------------------------------
__global__ __launch_bounds__(256, 4) void k_m1(Args a)
{
  int bi = blockIdx.x, t = threadIdx.x;
  int w = t >> 6, l = t & 63, l15 = l & 15, quad = l >> 4;
  __shared__ float sh_a0c0[512];
  __shared__ float red[2][4][4][16];

  bn0_finalize(a, t, sh_a0c0);
  __syncthreads();

  int b_, qt, half, st;
  tile_map(bi, b_, qt, half, st);
  f32x4 acc[2][4] = {};
  mfma_kloop(a.Aq, a.As, sh_a0c0, a.W1h, a.W1l, b_, qt, half, st, w, l15, quad, acc);

#pragma unroll
  for (int nt = 0; nt < 4; nt++) {
    float bias = a.b1[nt * 16 + l15];
    float s = 0, s2 = 0;
#pragma unroll
    for (int mt = 0; mt < 2; mt++)
#pragma unroll
      for (int r = 0; r < 4; r++) {
        float y = acc[mt][nt][r] + bias;
        s += y; s2 += y * y;
      }
    s  += __shfl_xor(s, 16);  s  += __shfl_xor(s, 32);
    s2 += __shfl_xor(s2, 16); s2 += __shfl_xor(s2, 32);
    if (quad == 0) { red[0][w][nt][l15] = s; red[1][w][nt][l15] = s2; }
  }
  __syncthreads();
  if (t < 128) {
    int which = t >> 6, j = t & 63, nt = j >> 4, jl = j & 15;
    float v = red[which][0][nt][jl] + red[which][1][nt][jl] +
              red[which][2][nt][jl] + red[which][3][nt][jl];
    atomicAdd(&a.ws1f[(bi & 15) * 128 + t], v);  // t<64: sum[j], t>=64: sumsq[j]
  }
}

// ---------------------------------------------------------------------------
// D3: main pass 2 — y2 + BN2 stats. 1024 half-tile blocks.
// ---------------------------------------------------------------------------
__global__ __launch_bounds__(256, 4) void k_m2(Args a)
{
  int bi = blockIdx.x, t = threadIdx.x;
  int w = t >> 6, l = t & 63, l15 = l & 15, quad = l >> 4;
  __shared__ float sh_a0c0[512];
  __shared__ float sh_tot[128];
  __shared__ float sh_a1c1[128];
  __shared__ float rs[16], rs2[16];

  bn0_finalize(a, t, sh_a0c0);
  if (t < 128) {
    float accv = 0;
#pragma unroll
    for (int c = 0; c < 16; c++) accv += a.ws1f[c * 128 + t];
    sh_tot[t] = accv;
  }
  __syncthreads();
  if (t < 64) {
    float mean = sh_tot[t] * INV_N;
    float var = sh_tot[64 + t] * INV_N - mean * mean;
    float aa = a.g1[t] * rsqrtf(var + BN_EPS);
    sh_a1c1[t] = aa;
    sh_a1c1[64 + t] = a.bt1[t] - mean * aa;
  }
  __syncthreads();

  int b_, qt, half, st;
  tile_map(bi, b_, qt, half, st);
  f32x4 acc[2][4] = {};
  mfma_kloop(a.Aq, a.As, sh_a0c0, a.W1h, a.W1l, b_, qt, half, st, w, l15, quad, acc);

  float a1v[4], c1v[4], w2v[4], biasv[4];
#pragma unroll
  for (int nt = 0; nt < 4; nt++) {
    int j = nt * 16 + l15;
    a1v[nt] = sh_a1c1[j]; c1v[nt] = sh_a1c1[64 + j];
    w2v[nt] = a.W2[j]; biasv[nt] = a.b1[j];
  }
  float b2v = a.b2[0];
  float ls = 0, ls2 = 0;
#pragma unroll
  for (int mt = 0; mt < 2; mt++) {
    float part[4] = {0, 0, 0, 0};
#pragma unroll
    for (int nt = 0; nt < 4; nt++)
#pragma unroll
      for (int r = 0; r < 4; r++) {
        float y = acc[mt][nt][r] + biasv[nt];
        float z = fmaxf(a1v[nt] * y + c1v[nt], 0.0f);
        part[r] += z * w2v[nt];
      }
#pragma unroll
    for (int r = 0; r < 4; r++) {
      float p = part[r];
      p += __shfl_xor(p, 1); p += __shfl_xor(p, 2);
      p += __shfl_xor(p, 4); p += __shfl_xor(p, 8);
      part[r] = p + b2v;
    }
    if (l15 == 0) {
      int q = qt * 16 + half * 8 + w * 2 + mt;
      int P = ((b_ * 256 + q) * 128) + st * 16 + quad * 4;
      f32x4 o;
#pragma unroll
      for (int r = 0; r < 4; r++) { o[r] = part[r]; ls += part[r]; ls2 += part[r] * part[r]; }
      *(f32x4*)(a.y2 + P) = o;
    }
  }
  if (l15 == 0) { rs[t >> 4] = ls; rs2[t >> 4] = ls2; }
  __syncthreads();
  if (t == 0) {
    float s = 0, s2 = 0;
#pragma unroll
    for (int i = 0; i < 16; i++) { s += rs[i]; s2 += rs2[i]; }
    atomicAdd(&a.ws2f[(bi & 15) * 2], s);       // 64 adds/address
    atomicAdd(&a.ws2f[(bi & 15) * 2 + 1], s2);
  }
}

// ---------------------------------------------------------------------------
// D4: BN2 finalize (redundant, 32 floats) + out. 128 blocks, 4 floats/thread.
// ---------------------------------------------------------------------------
__global__ __launch_bounds__(256) void k_out(Args a)
{
  int t = threadIdx.x;
  float s = 0, s2 = 0;
#pragma unroll
  for (int c = 0; c < 16; c++) { s += a.ws2f[c * 2]; s2 += a.ws2f[c * 2 + 1]; }
  float mean = s * INV_N;
  float var = s2 * INV_N - mean * mean;
  float aa = a.g2[0] * rsqrtf(var + BN_EPS);
  float cc = a.bt2[0] - mean * aa;
  int i = (blockIdx.x * 256 + t) * 4;     // 128*256*4 = 131072 exactly
  f32x4 v = *(const f32x4*)(a.y2 + i);
  f32x4 o;
#pragma unroll
  for (int r = 0; r < 4; r++) o[r] = fmaxf(aa * v[r] + cc, 0.0f);
  *(f32x4*)(a.out + i) = o;
}

extern "C" void kernel_launch(void* const* d_in, const int* in_sizes, int n_in,
                              void* d_out, int out_size, void* d_ws, size_t ws_size,
                              hipStream_t stream)
{
  float* ws = (float*)d_ws;
  Args a;
  a.Sf  = (const float*)d_in[0];   // support [4,128,256]
  a.Qf  = (const float*)d_in[1];   // query   [4,256,256]
  a.W0  = (const float*)d_in[2];   // [256,512]
  a.b0  = (const float*)d_in[3];
  a.g0  = (const float*)d_in[4];
  a.bt0 = (const float*)d_in[5];
  a.W1  = (const float*)d_in[6];   // [64,256]
  a.b1  = (const float*)d_in[7];
  a.g1  = (const float*)d_in[8];
  a.bt1 = (const float*)d_in[9];
  a.W2  = (const float*)d_in[10];  // [1,64]
  a.b2  = (const float*)d_in[11];
  a.g2  = (const float*)d_in[12];
  a.bt2 = (const float*)d_in[13];

  a.Aq   = ws;                     // 262144 f
  a.As   = ws + 262144;            // 131072 f
  a.y2   = ws + 393216;            // 131072 f
  a.ws0s = ws + 524288;            // 96*512 = 49152 f (BN0 slots, fully overwritten)
  a.ws1f = ws + 573440;            // 2048 f (16-way spread atomics, zeroed by D1 blk96)
  a.ws2f = ws + 575488;            // 32 f   (16-way spread atomics, zeroed by D1 blk96)
  a.W1h  = (ushort*)(ws + 575552); // 16384 u16 = 8192 f
  a.W1l  = (ushort*)(ws + 583744); // 16384 u16 -> total ~2.3 MB
  a.out  = (float*)d_out;

  k_g0 <<<97, 256, 0, stream>>>(a);
  k_m1 <<<1024, 256, 0, stream>>>(a);
  k_m2 <<<1024, 256, 0, stream>>>(a);
  k_out<<<128, 256, 0, stream>>>(a);
}

// Round 12
// 144.183 us; speedup vs baseline: 1.3392x; 1.3392x over previous
//
#include <hip/hip_runtime.h>
#include <hip/hip_bf16.h>

// RelationNet fused pipeline, fp32 in/out — FOUR dispatches, no grid barriers.
// B=4 Q=256 S=128 C=256; feats 512 -> 256 -> 64 -> 1; BN (training) + ReLU each layer.
//
// Factorization: concat(uq,us)@W0^T = query@W0a^T + support@W0b^T => Aq[b,q,o], As[b,s,o]
// (b0 folded into As). BN0 stats analytic from per-b sums.
// GEMM0 ~fp32 via 3-term in-register hi/lo bf16 split. GEMM1: z-side bf16-RNE on the
// fly, W1-side hi/lo bf16 pre-split (k_g0 blk96) and STAGED IN LDS per block (R12).
//
// R10 (512 blk, W1 from L2): k_m=44us. R11 (1024 blk): 54us despite 2x occupancy.
// Lesson: per-block fixed cost + per-wave W1 L2 streaming dominates, not latency
// hiding. R12: R10 structure + W1 in LDS (row padded +8 shorts -> 2-way bank
// aliasing, free per m136), ds_read_b128 in the K-loop.

typedef __attribute__((ext_vector_type(4))) float f32x4;
typedef __attribute__((ext_vector_type(8))) short s16x8;

#define BN_EPS 1e-5f
#define INV_N  (1.0f/131072.0f)
#define W1PITCH 264   // 256 shorts + 8 pad

__device__ __forceinline__ unsigned pk_bf16(float a, float b) {
  float2 t; t.x = a; t.y = b;
  __hip_bfloat162 h = __float22bfloat162_rn(t);
  return *reinterpret_cast<unsigned*>(&h);
}
__device__ __forceinline__ void split2(float a, float b, unsigned& uh, unsigned& ul) {
  uh = pk_bf16(a, b);
  float ha = __uint_as_float(uh << 16);
  float hb = __uint_as_float(uh & 0xFFFF0000u);
  ul = pk_bf16(a - ha, b - hb);
}

union frag_u { s16x8 v; unsigned u[4]; };

struct Args {
  const float *Sf, *Qf, *W0, *b0, *g0, *bt0, *W1, *b1, *g1, *bt1, *W2, *b2, *g2, *bt2;
  float *Aq, *As, *y2, *ws0s, *ws1f, *ws2f, *out;
  ushort *W1h, *W1l;
};

// ---------------------------------------------------------------------------
// D1: GEMM0. 97 blocks x 256 thr. Blocks 0..95: block bi = one 16-row chunk,
// wave w = one 16x64 tile. mtile<64: Aq; else As (+b0). W0 split in-register.
// BN0 partial slots (no atomics): ws0s[bi*512 + o] / [..+256+o] = sum/sumsq.
// Block 96: split W1 -> W1h/W1l (bf16, global) and zero ws1f/ws2f atomic pads.
// ---------------------------------------------------------------------------
__global__ __launch_bounds__(256) void k_g0(Args a)
{
  int bi = blockIdx.x, t = threadIdx.x;
  if (bi == 96) {
    for (int k = 0; k < 32; k++) {
      int idx = t * 64 + k * 2;
      unsigned uh, ul;
      split2(a.W1[idx], a.W1[idx + 1], uh, ul);
      a.W1h[idx] = (ushort)(uh & 0xFFFFu); a.W1h[idx + 1] = (ushort)(uh >> 16);
      a.W1l[idx] = (ushort)(ul & 0xFFFFu); a.W1l[idx + 1] = (ushort)(ul >> 16);
    }
    for (int i = t; i < 2048; i += 256) a.ws1f[i] = 0.0f;
    if (t < 32) a.ws2f[t] = 0.0f;
    return;
  }
  int w = t >> 6, l = t & 63, l15 = l & 15, quad = l >> 4;
  bool isQ = (bi < 64);
  const float* X; float* Out; int m0, koff;
  if (isQ) { m0 = bi * 16; X = a.Qf; Out = a.Aq; koff = 0; }
  else     { m0 = (bi - 64) * 16; X = a.Sf; Out = a.As; koff = 256; }
  int n0 = w * 64;

  f32x4 acc[4] = {};
#pragma unroll
  for (int ko = 0; ko < 256; ko += 32) {
    const float* row = X + (m0 + l15) * 256 + ko + quad * 8;
    f32x4 v0 = *(const f32x4*)(row);
    f32x4 v1 = *(const f32x4*)(row + 4);
    frag_u ah, al;
#pragma unroll
    for (int j = 0; j < 2; j++) {
      split2(v0[2 * j], v0[2 * j + 1], ah.u[j], al.u[j]);
      split2(v1[2 * j], v1[2 * j + 1], ah.u[2 + j], al.u[2 + j]);
    }
#pragma unroll
    for (int nt = 0; nt < 4; nt++) {
      const float* wrow = a.W0 + (n0 + nt * 16 + l15) * 512 + koff + ko + quad * 8;
      f32x4 w0v = *(const f32x4*)(wrow);
      f32x4 w1v = *(const f32x4*)(wrow + 4);
      frag_u bh, bl;
      split2(w0v[0], w0v[1], bh.u[0], bl.u[0]);
      split2(w0v[2], w0v[3], bh.u[1], bl.u[1]);
      split2(w1v[0], w1v[1], bh.u[2], bl.u[2]);
      split2(w1v[2], w1v[3], bh.u[3], bl.u[3]);
      acc[nt] = __builtin_amdgcn_mfma_f32_16x16x32_bf16(ah.v, bh.v, acc[nt], 0, 0, 0);
      acc[nt] = __builtin_amdgcn_mfma_f32_16x16x32_bf16(al.v, bh.v, acc[nt], 0, 0, 0);
      acc[nt] = __builtin_amdgcn_mfma_f32_16x16x32_bf16(ah.v, bl.v, acc[nt], 0, 0, 0);
    }
  }
#pragma unroll
  for (int nt = 0; nt < 4; nt++) {
    int o = n0 + nt * 16 + l15;
    float bias = isQ ? 0.0f : a.b0[o];
    float cs = 0, cs2 = 0;
#pragma unroll
    for (int r = 0; r < 4; r++) {
      float y = acc[nt][r] + bias;
      Out[(m0 + quad * 4 + r) * 256 + o] = y;
      cs += y; cs2 += y * y;
    }
    cs  += __shfl_xor(cs, 16);  cs  += __shfl_xor(cs, 32);
    cs2 += __shfl_xor(cs2, 16); cs2 += __shfl_xor(cs2, 32);
    if (quad == 0) {
      a.ws0s[bi * 512 + o] = cs;
      a.ws0s[bi * 512 + 256 + o] = cs2;
    }
  }
}

// Stage pre-split W1 (global) into padded LDS arrays. 256 thr: row=t>>2, 64
// shorts per quarter-row per array.
__device__ __forceinline__ void stage_w1(const Args& a, int t, ushort* w1h, ushort* w1l)
{
  int row = t >> 2, qd = t & 3;
  const s16x8* srch = (const s16x8*)(a.W1h + row * 256 + qd * 64);
  const s16x8* srcl = (const s16x8*)(a.W1l + row * 256 + qd * 64);
  s16x8* dsth = (s16x8*)(w1h + row * W1PITCH + qd * 64);
  s16x8* dstl = (s16x8*)(w1l + row * W1PITCH + qd * 64);
#pragma unroll
  for (int k = 0; k < 8; k++) { dsth[k] = srch[k]; dstl[k] = srcl[k]; }
}

// Main-GEMM K-loop (layer-1): z0 generated in bf16-RNE A-frag layout in regs;
// y1 tile = z0 @ W1^T via MFMA, W1 frags from LDS (ds_read_b128).
// Mapping: q = qt*16 + w*4 + mt; A-frag m(lane&15) = s-in-tile; k = channel.
// D: col(lane&15) = j, row(quad*4+r) = s-in-tile.
__device__ __forceinline__ void mfma_kloop(
    const float* __restrict__ Aq, const float* __restrict__ As,
    const float* sh_a0c0, const ushort* w1h, const ushort* w1l,
    int b, int qt, int st, int w, int l15, int quad, f32x4 acc[4][4])
{
  const float* asrow = As + ((b << 7) + st * 16 + l15) * 256;
  const float* aqrow[4];
#pragma unroll
  for (int mt = 0; mt < 4; mt++)
    aqrow[mt] = Aq + ((b << 8) + qt * 16 + w * 4 + mt) * 256;

#pragma unroll
  for (int ko = 0; ko < 256; ko += 32) {
    int obase = ko + quad * 8;
    f32x4 a0v0 = *(const f32x4*)(sh_a0c0 + obase);
    f32x4 a0v1 = *(const f32x4*)(sh_a0c0 + obase + 4);
    f32x4 c0v0 = *(const f32x4*)(sh_a0c0 + 256 + obase);
    f32x4 c0v1 = *(const f32x4*)(sh_a0c0 + 256 + obase + 4);
    f32x4 as0 = *(const f32x4*)(asrow + obase);
    f32x4 as1 = *(const f32x4*)(asrow + obase + 4);

    s16x8 zh[4];
#pragma unroll
    for (int mt = 0; mt < 4; mt++) {
      f32x4 aq0 = *(const f32x4*)(aqrow[mt] + obase);
      f32x4 aq1 = *(const f32x4*)(aqrow[mt] + obase + 4);
      f32x4 z0 = (aq0 + as0) * a0v0 + c0v0;
      f32x4 z1 = (aq1 + as1) * a0v1 + c0v1;
      frag_u zz;
      zz.u[0] = pk_bf16(fmaxf(z0[0], 0.0f), fmaxf(z0[1], 0.0f));
      zz.u[1] = pk_bf16(fmaxf(z0[2], 0.0f), fmaxf(z0[3], 0.0f));
      zz.u[2] = pk_bf16(fmaxf(z1[0], 0.0f), fmaxf(z1[1], 0.0f));
      zz.u[3] = pk_bf16(fmaxf(z1[2], 0.0f), fmaxf(z1[3], 0.0f));
      zh[mt] = zz.v;
    }
#pragma unroll
    for (int nt = 0; nt < 4; nt++) {
      s16x8 bh = *(const s16x8*)(w1h + (nt * 16 + l15) * W1PITCH + obase);
      s16x8 bl = *(const s16x8*)(w1l + (nt * 16 + l15) * W1PITCH + obase);
#pragma unroll
      for (int mt = 0; mt < 4; mt++) {
        acc[mt][nt] = __builtin_amdgcn_mfma_f32_16x16x32_bf16(zh[mt], bh, acc[mt][nt], 0, 0, 0);
        acc[mt][nt] = __builtin_amdgcn_mfma_f32_16x16x32_bf16(zh[mt], bl, acc[mt][nt], 0, 0, 0);
      }
    }
  }
}

// Redundant per-block BN0 finalize from D1's slots -> LDS a0/c0.
__device__ __forceinline__ void bn0_finalize(const Args& a, int t, float* sh_a0c0)
{
  int o = t;
  float sumY = 0, cross = 0, SQ2 = 0, SS2 = 0;
#pragma unroll
  for (int b = 0; b < 4; b++) {
    float sq1 = 0, sq2 = 0, ss1 = 0, ss2 = 0;
#pragma unroll
    for (int c = 0; c < 16; c++) {
      sq1 += a.ws0s[(b * 16 + c) * 512 + o];
      sq2 += a.ws0s[(b * 16 + c) * 512 + 256 + o];
    }
#pragma unroll
    for (int c = 0; c < 8; c++) {
      ss1 += a.ws0s[(64 + b * 8 + c) * 512 + o];
      ss2 += a.ws0s[(64 + b * 8 + c) * 512 + 256 + o];
    }
    SQ2 += sq2; SS2 += ss2;
    sumY += 128.0f * sq1 + 256.0f * ss1;
    cross += sq1 * ss1;
  }
  float mean = sumY * INV_N;
  float var = (128.0f * SQ2 + 256.0f * SS2 + 2.0f * cross) * INV_N - mean * mean;
  float aa = a.g0[o] * rsqrtf(var + BN_EPS);
  sh_a0c0[o] = aa;
  sh_a0c0[256 + o] = a.bt0[o] - mean * aa;
}

// ---------------------------------------------------------------------------
// D2: main pass 1 — BN1 stats. 512 blocks, one (b,qt,st) tile each.
// BN1 partials -> 16-way-spread atomicAdd ws1f (32 adds/address).
// ---------------------------------------------------------------------------
__global__ __launch_bounds__(256) void k_m1(Args a)
{
  int bi = blockIdx.x, t = threadIdx.x;
  int w = t >> 6, l = t & 63, l15 = l & 15, quad = l >> 4;
  __shared__ ushort w1h[64 * W1PITCH];
  __shared__ ushort w1l[64 * W1PITCH];
  __shared__ float sh_a0c0[512];
  __shared__ float red[2][4][4][16];

  stage_w1(a, t, w1h, w1l);
  bn0_finalize(a, t, sh_a0c0);
  __syncthreads();

  int b_ = bi >> 7, rem = bi & 127, qt = rem >> 3, st = rem & 7;
  f32x4 acc[4][4] = {};
  mfma_kloop(a.Aq, a.As, sh_a0c0, w1h, w1l, b_, qt, st, w, l15, quad, acc);

#pragma unroll
  for (int nt = 0; nt < 4; nt++) {
    float bias = a.b1[nt * 16 + l15];
    float s = 0, s2 = 0;
#pragma unroll
    for (int mt = 0; mt < 4; mt++)
#pragma unroll
      for (int r = 0; r < 4; r++) {
        float y = acc[mt][nt][r] + bias;
        s += y; s2 += y * y;
      }
    s  += __shfl_xor(s, 16);  s  += __shfl_xor(s, 32);
    s2 += __shfl_xor(s2, 16); s2 += __shfl_xor(s2, 32);
    if (quad == 0) { red[0][w][nt][l15] = s; red[1][w][nt][l15] = s2; }
  }
  __syncthreads();
  if (t < 128) {
    int which = t >> 6, j = t & 63, nt = j >> 4, jl = j & 15;
    float v = red[which][0][nt][jl] + red[which][1][nt][jl] +
              red[which][2][nt][jl] + red[which][3][nt][jl];
    atomicAdd(&a.ws1f[(bi & 15) * 128 + t], v);  // t<64: sum[j], t>=64: sumsq[j]
  }
}

// ---------------------------------------------------------------------------
// D3: main pass 2 — y2 + BN2 stats. 512 blocks, one tile each.
// ---------------------------------------------------------------------------
__global__ __launch_bounds__(256) void k_m2(Args a)
{
  int bi = blockIdx.x, t = threadIdx.x;
  int w = t >> 6, l = t & 63, l15 = l & 15, quad = l >> 4;
  __shared__ ushort w1h[64 * W1PITCH];
  __shared__ ushort w1l[64 * W1PITCH];
  __shared__ float sh_a0c0[512];
  __shared__ float sh_tot[128];
  __shared__ float sh_a1c1[128];
  __shared__ float rs[16], rs2[16];

  stage_w1(a, t, w1h, w1l);
  bn0_finalize(a, t, sh_a0c0);
  if (t < 128) {
    float accv = 0;
#pragma unroll
    for (int c = 0; c < 16; c++) accv += a.ws1f[c * 128 + t];
    sh_tot[t] = accv;
  }
  __syncthreads();
  if (t < 64) {
    float mean = sh_tot[t] * INV_N;
    float var = sh_tot[64 + t] * INV_N - mean * mean;
    float aa = a.g1[t] * rsqrtf(var + BN_EPS);
    sh_a1c1[t] = aa;
    sh_a1c1[64 + t] = a.bt1[t] - mean * aa;
  }
  __syncthreads();

  int b_ = bi >> 7, rem = bi & 127, qt = rem >> 3, st = rem & 7;
  f32x4 acc[4][4] = {};
  mfma_kloop(a.Aq, a.As, sh_a0c0, w1h, w1l, b_, qt, st, w, l15, quad, acc);

  float a1v[4], c1v[4], w2v[4], biasv[4];
#pragma unroll
  for (int nt = 0; nt < 4; nt++) {
    int j = nt * 16 + l15;
    a1v[nt] = sh_a1c1[j]; c1v[nt] = sh_a1c1[64 + j];
    w2v[nt] = a.W2[j]; biasv[nt] = a.b1[j];
  }
  float b2v = a.b2[0];
  float ls = 0, ls2 = 0;
#pragma unroll
  for (int mt = 0; mt < 4; mt++) {
    float part[4] = {0, 0, 0, 0};
#pragma unroll
    for (int nt = 0; nt < 4; nt++)
#pragma unroll
      for (int r = 0; r < 4; r++) {
        float y = acc[mt][nt][r] + biasv[nt];
        float z = fmaxf(a1v[nt] * y + c1v[nt], 0.0f);
        part[r] += z * w2v[nt];
      }
#pragma unroll
    for (int r = 0; r < 4; r++) {
      float p = part[r];
      p += __shfl_xor(p, 1); p += __shfl_xor(p, 2);
      p += __shfl_xor(p, 4); p += __shfl_xor(p, 8);
      part[r] = p + b2v;
    }
    if (l15 == 0) {
      int q = qt * 16 + w * 4 + mt;
      int P = ((b_ * 256 + q) * 128) + st * 16 + quad * 4;
      f32x4 o;
#pragma unroll
      for (int r = 0; r < 4; r++) { o[r] = part[r]; ls += part[r]; ls2 += part[r] * part[r]; }
      *(f32x4*)(a.y2 + P) = o;
    }
  }
  if (l15 == 0) { rs[t >> 4] = ls; rs2[t >> 4] = ls2; }
  __syncthreads();
  if (t == 0) {
    float s = 0, s2 = 0;
#pragma unroll
    for (int i = 0; i < 16; i++) { s += rs[i]; s2 += rs2[i]; }
    atomicAdd(&a.ws2f[(bi & 15) * 2], s);       // 32 adds/address
    atomicAdd(&a.ws2f[(bi & 15) * 2 + 1], s2);
  }
}

// ---------------------------------------------------------------------------
// D4: BN2 finalize (redundant, 32 floats) + out. 128 blocks, 4 floats/thread.
// ---------------------------------------------------------------------------
__global__ __launch_bounds__(256) void k_out(Args a)
{
  int t = threadIdx.x;
  float s = 0, s2 = 0;
#pragma unroll
  for (int c = 0; c < 16; c++) { s += a.ws2f[c * 2]; s2 += a.ws2f[c * 2 + 1]; }
  float mean = s * INV_N;
  float var = s2 * INV_N - mean * mean;
  float aa = a.g2[0] * rsqrtf(var + BN_EPS);
  float cc = a.bt2[0] - mean * aa;
  int i = (blockIdx.x * 256 + t) * 4;     // 128*256*4 = 131072 exactly
  f32x4 v = *(const f32x4*)(a.y2 + i);
  f32x4 o;
#pragma unroll
  for (int r = 0; r < 4; r++) o[r] = fmaxf(aa * v[r] + cc, 0.0f);
  *(f32x4*)(a.out + i) = o;
}

extern "C" void kernel_launch(void* const* d_in, const int* in_sizes, int n_in,
                              void* d_out, int out_size, void* d_ws, size_t ws_size,
                              hipStream_t stream)
{
  float* ws = (float*)d_ws;
  Args a;
  a.Sf  = (const float*)d_in[0];   // support [4,128,256]
  a.Qf  = (const float*)d_in[1];   // query   [4,256,256]
  a.W0  = (const float*)d_in[2];   // [256,512]
  a.b0  = (const float*)d_in[3];
  a.g0  = (const float*)d_in[4];
  a.bt0 = (const float*)d_in[5];
  a.W1  = (const float*)d_in[6];   // [64,256]
  a.b1  = (const float*)d_in[7];
  a.g1  = (const float*)d_in[8];
  a.bt1 = (const float*)d_in[9];
  a.W2  = (const float*)d_in[10];  // [1,64]
  a.b2  = (const float*)d_in[11];
  a.g2  = (const float*)d_in[12];
  a.bt2 = (const float*)d_in[13];

  a.Aq   = ws;                     // 262144 f
  a.As   = ws + 262144;            // 131072 f
  a.y2   = ws + 393216;            // 131072 f
  a.ws0s = ws + 524288;            // 96*512 = 49152 f (BN0 slots, fully overwritten)
  a.ws1f = ws + 573440;            // 2048 f (16-way spread atomics, zeroed by D1 blk96)
  a.ws2f = ws + 575488;            // 32 f   (16-way spread atomics, zeroed by D1 blk96)
  a.W1h  = (ushort*)(ws + 575552); // 16384 u16 = 8192 f
  a.W1l  = (ushort*)(ws + 583744); // 16384 u16 -> total ~2.3 MB
  a.out  = (float*)d_out;

  k_g0 <<<97, 256, 0, stream>>>(a);
  k_m1 <<<512, 256, 0, stream>>>(a);
  k_m2 <<<512, 256, 0, stream>>>(a);
  k_out<<<128, 256, 0, stream>>>(a);
}

// Round 13
// 137.601 us; speedup vs baseline: 1.4033x; 1.0478x over previous
//
#include <hip/hip_runtime.h>
#include <hip/hip_bf16.h>

// RelationNet fused pipeline, fp32 in/out — FOUR dispatches, no grid barriers.
// B=4 Q=256 S=128 C=256; feats 512 -> 256 -> 64 -> 1; BN (training) + ReLU each layer.
//
// Factorization: concat(uq,us)@W0^T = query@W0a^T + support@W0b^T => Aq[b,q,o], As[b,s,o]
// (b0 folded into As). BN0 stats analytic from per-b sums.
// GEMM0 ~fp32 via 3-term in-register hi/lo bf16 split. GEMM1 (k_m1): z-side bf16-RNE,
// W1 pre-split hi/lo bf16 staged in LDS in FRAGMENT ORDER (lane-contiguous 16B ->
// conflict-free ds_read_b128; R12's 264-short pitch was 132 dwords = 4 mod 32 -> 8-way).
// R13: k_m1 stores y1 (bias-added, bf16, frag layout, 16 MB); pass 2 (k_p2) is a pure
// streaming kernel — experiment: does the unexplained ~40us/dispatch track K-loop work
// or grid size? (R4-R12: heavy 512-blk dispatches all 44-54us with ~10us countable work.)

typedef __attribute__((ext_vector_type(4))) float f32x4;
typedef __attribute__((ext_vector_type(8))) short s16x8;

#define BN_EPS 1e-5f
#define INV_N  (1.0f/131072.0f)

__device__ __forceinline__ unsigned pk_bf16(float a, float b) {
  float2 t; t.x = a; t.y = b;
  __hip_bfloat162 h = __float22bfloat162_rn(t);
  return *reinterpret_cast<unsigned*>(&h);  // low16 = bf16(a), high16 = bf16(b)
}
__device__ __forceinline__ void split2(float a, float b, unsigned& uh, unsigned& ul) {
  uh = pk_bf16(a, b);
  float ha = __uint_as_float(uh << 16);
  float hb = __uint_as_float(uh & 0xFFFF0000u);
  ul = pk_bf16(a - ha, b - hb);
}

union frag_u { s16x8 v; unsigned u[4]; };

struct Args {
  const float *Sf, *Qf, *W0, *b0, *g0, *bt0, *W1, *b1, *g1, *bt1, *W2, *b2, *g2, *bt2;
  float *Aq, *As, *y2, *ws0s, *ws1f, *ws2f, *out;
  ushort *W1h, *W1l, *y1f;
};

// ---------------------------------------------------------------------------
// D1: GEMM0. 97 blocks x 256 thr. Blocks 0..95: block bi = one 16-row chunk,
// wave w = one 16x64 tile. mtile<64: Aq; else As (+b0). W0 split in-register.
// BN0 partial slots (no atomics): ws0s[bi*512 + o] / [..+256+o] = sum/sumsq.
// Block 96: split W1 -> W1h/W1l (bf16, global) and zero ws1f/ws2f atomic pads.
// ---------------------------------------------------------------------------
__global__ __launch_bounds__(256) void k_g0(Args a)
{
  int bi = blockIdx.x, t = threadIdx.x;
  if (bi == 96) {
    for (int k = 0; k < 32; k++) {
      int idx = t * 64 + k * 2;
      unsigned uh, ul;
      split2(a.W1[idx], a.W1[idx + 1], uh, ul);
      a.W1h[idx] = (ushort)(uh & 0xFFFFu); a.W1h[idx + 1] = (ushort)(uh >> 16);
      a.W1l[idx] = (ushort)(ul & 0xFFFFu); a.W1l[idx + 1] = (ushort)(ul >> 16);
    }
    for (int i = t; i < 2048; i += 256) a.ws1f[i] = 0.0f;
    if (t < 32) a.ws2f[t] = 0.0f;
    return;
  }
  int w = t >> 6, l = t & 63, l15 = l & 15, quad = l >> 4;
  bool isQ = (bi < 64);
  const float* X; float* Out; int m0, koff;
  if (isQ) { m0 = bi * 16; X = a.Qf; Out = a.Aq; koff = 0; }
  else     { m0 = (bi - 64) * 16; X = a.Sf; Out = a.As; koff = 256; }
  int n0 = w * 64;

  f32x4 acc[4] = {};
#pragma unroll
  for (int ko = 0; ko < 256; ko += 32) {
    const float* row = X + (m0 + l15) * 256 + ko + quad * 8;
    f32x4 v0 = *(const f32x4*)(row);
    f32x4 v1 = *(const f32x4*)(row + 4);
    frag_u ah, al;
#pragma unroll
    for (int j = 0; j < 2; j++) {
      split2(v0[2 * j], v0[2 * j + 1], ah.u[j], al.u[j]);
      split2(v1[2 * j], v1[2 * j + 1], ah.u[2 + j], al.u[2 + j]);
    }
#pragma unroll
    for (int nt = 0; nt < 4; nt++) {
      const float* wrow = a.W0 + (n0 + nt * 16 + l15) * 512 + koff + ko + quad * 8;
      f32x4 w0v = *(const f32x4*)(wrow);
      f32x4 w1v = *(const f32x4*)(wrow + 4);
      frag_u bh, bl;
      split2(w0v[0], w0v[1], bh.u[0], bl.u[0]);
      split2(w0v[2], w0v[3], bh.u[1], bl.u[1]);
      split2(w1v[0], w1v[1], bh.u[2], bl.u[2]);
      split2(w1v[2], w1v[3], bh.u[3], bl.u[3]);
      acc[nt] = __builtin_amdgcn_mfma_f32_16x16x32_bf16(ah.v, bh.v, acc[nt], 0, 0, 0);
      acc[nt] = __builtin_amdgcn_mfma_f32_16x16x32_bf16(al.v, bh.v, acc[nt], 0, 0, 0);
      acc[nt] = __builtin_amdgcn_mfma_f32_16x16x32_bf16(ah.v, bl.v, acc[nt], 0, 0, 0);
    }
  }
#pragma unroll
  for (int nt = 0; nt < 4; nt++) {
    int o = n0 + nt * 16 + l15;
    float bias = isQ ? 0.0f : a.b0[o];
    float cs = 0, cs2 = 0;
#pragma unroll
    for (int r = 0; r < 4; r++) {
      float y = acc[nt][r] + bias;
      Out[(m0 + quad * 4 + r) * 256 + o] = y;
      cs += y; cs2 += y * y;
    }
    cs  += __shfl_xor(cs, 16);  cs  += __shfl_xor(cs, 32);
    cs2 += __shfl_xor(cs2, 16); cs2 += __shfl_xor(cs2, 32);
    if (quad == 0) {
      a.ws0s[bi * 512 + o] = cs;
      a.ws0s[bi * 512 + 256 + o] = cs2;
    }
  }
}

// Redundant per-block BN0 finalize from D1's slots -> LDS a0/c0.
__device__ __forceinline__ void bn0_finalize(const Args& a, int t, float* sh_a0c0)
{
  int o = t;
  float sumY = 0, cross = 0, SQ2 = 0, SS2 = 0;
#pragma unroll
  for (int b = 0; b < 4; b++) {
    float sq1 = 0, sq2 = 0, ss1 = 0, ss2 = 0;
#pragma unroll
    for (int c = 0; c < 16; c++) {
      sq1 += a.ws0s[(b * 16 + c) * 512 + o];
      sq2 += a.ws0s[(b * 16 + c) * 512 + 256 + o];
    }
#pragma unroll
    for (int c = 0; c < 8; c++) {
      ss1 += a.ws0s[(64 + b * 8 + c) * 512 + o];
      ss2 += a.ws0s[(64 + b * 8 + c) * 512 + 256 + o];
    }
    SQ2 += sq2; SS2 += ss2;
    sumY += 128.0f * sq1 + 256.0f * ss1;
    cross += sq1 * ss1;
  }
  float mean = sumY * INV_N;
  float var = (128.0f * SQ2 + 256.0f * SS2 + 2.0f * cross) * INV_N - mean * mean;
  float aa = a.g0[o] * rsqrtf(var + BN_EPS);
  sh_a0c0[o] = aa;
  sh_a0c0[256 + o] = a.bt0[o] - mean * aa;
}

// ---------------------------------------------------------------------------
// D2: main GEMM (single pass now). 512 blocks, one (b,qt,st) tile each.
// z0 bf16-RNE in regs; W1 frags from LDS in FRAGMENT ORDER: frag id
// fr = (kk*4+nt)*64 + lane -> 8 shorts at w1?f + fr*8 (lane-contiguous 16B,
// conflict-free). y1 (bias-added, bf16-RNE) stored to global in frag layout:
// y1f[slot*256 + l*4 + r], slot = (bi*4+w)*16 + mt*4 + nt.
// BN1 stats from the STORED bf16 values -> 16-way-spread atomicAdd ws1f.
// ---------------------------------------------------------------------------
__global__ __launch_bounds__(256) void k_m1(Args a)
{
  int bi = blockIdx.x, t = threadIdx.x;
  int w = t >> 6, l = t & 63, l15 = l & 15, quad = l >> 4;
  __shared__ ushort w1hf[2048 * 8];   // 32 KB, frag order
  __shared__ ushort w1lf[2048 * 8];   // 32 KB
  __shared__ float sh_a0c0[512];
  __shared__ float red[2][4][4][16];

  // stage W1 -> LDS frag order
#pragma unroll
  for (int i = 0; i < 8; i++) {
    int fr = i * 256 + t;
    int kk = fr >> 8, r = fr & 255, nt = r >> 6, ln = r & 63;
    int src = (nt * 16 + (ln & 15)) * 256 + kk * 32 + (ln >> 4) * 8;
    *(s16x8*)(w1hf + fr * 8) = *(const s16x8*)(a.W1h + src);
    *(s16x8*)(w1lf + fr * 8) = *(const s16x8*)(a.W1l + src);
  }
  bn0_finalize(a, t, sh_a0c0);
  __syncthreads();

  int b_ = bi >> 7, rem = bi & 127, qt = rem >> 3, st = rem & 7;
  const float* asrow = a.As + ((b_ << 7) + st * 16 + l15) * 256;
  const float* aqrow[4];
#pragma unroll
  for (int mt = 0; mt < 4; mt++)
    aqrow[mt] = a.Aq + ((b_ << 8) + qt * 16 + w * 4 + mt) * 256;

  f32x4 acc[4][4] = {};
#pragma unroll
  for (int kk = 0; kk < 8; kk++) {
    int obase = kk * 32 + quad * 8;
    f32x4 a0v0 = *(const f32x4*)(sh_a0c0 + obase);
    f32x4 a0v1 = *(const f32x4*)(sh_a0c0 + obase + 4);
    f32x4 c0v0 = *(const f32x4*)(sh_a0c0 + 256 + obase);
    f32x4 c0v1 = *(const f32x4*)(sh_a0c0 + 256 + obase + 4);
    f32x4 as0 = *(const f32x4*)(asrow + obase);
    f32x4 as1 = *(const f32x4*)(asrow + obase + 4);

    s16x8 zh[4];
#pragma unroll
    for (int mt = 0; mt < 4; mt++) {
      f32x4 aq0 = *(const f32x4*)(aqrow[mt] + obase);
      f32x4 aq1 = *(const f32x4*)(aqrow[mt] + obase + 4);
      f32x4 z0 = (aq0 + as0) * a0v0 + c0v0;
      f32x4 z1 = (aq1 + as1) * a0v1 + c0v1;
      frag_u zz;
      zz.u[0] = pk_bf16(fmaxf(z0[0], 0.0f), fmaxf(z0[1], 0.0f));
      zz.u[1] = pk_bf16(fmaxf(z0[2], 0.0f), fmaxf(z0[3], 0.0f));
      zz.u[2] = pk_bf16(fmaxf(z1[0], 0.0f), fmaxf(z1[1], 0.0f));
      zz.u[3] = pk_bf16(fmaxf(z1[2], 0.0f), fmaxf(z1[3], 0.0f));
      zh[mt] = zz.v;
    }
#pragma unroll
    for (int nt = 0; nt < 4; nt++) {
      s16x8 bh = *(const s16x8*)(w1hf + ((kk * 4 + nt) * 64 + l) * 8);
      s16x8 bl = *(const s16x8*)(w1lf + ((kk * 4 + nt) * 64 + l) * 8);
#pragma unroll
      for (int mt = 0; mt < 4; mt++) {
        acc[mt][nt] = __builtin_amdgcn_mfma_f32_16x16x32_bf16(zh[mt], bh, acc[mt][nt], 0, 0, 0);
        acc[mt][nt] = __builtin_amdgcn_mfma_f32_16x16x32_bf16(zh[mt], bl, acc[mt][nt], 0, 0, 0);
      }
    }
  }

  // epilogue: add bias, bf16-round, store y1 frags, stats from stored values
  float biasv[4];
#pragma unroll
  for (int nt = 0; nt < 4; nt++) biasv[nt] = a.b1[nt * 16 + l15];
  float s[4] = {0, 0, 0, 0}, s2[4] = {0, 0, 0, 0};
#pragma unroll
  for (int mt = 0; mt < 4; mt++) {
#pragma unroll
    for (int nt = 0; nt < 4; nt++) {
      float y0 = acc[mt][nt][0] + biasv[nt];
      float y1 = acc[mt][nt][1] + biasv[nt];
      float y2v = acc[mt][nt][2] + biasv[nt];
      float y3 = acc[mt][nt][3] + biasv[nt];
      unsigned u01 = pk_bf16(y0, y1), u23 = pk_bf16(y2v, y3);
      uint2 pk; pk.x = u01; pk.y = u23;
      int slot = (bi * 4 + w) * 16 + mt * 4 + nt;
      *(uint2*)(a.y1f + (size_t)(slot * 64 + l) * 4) = pk;
      float f0 = __uint_as_float(u01 << 16), f1 = __uint_as_float(u01 & 0xFFFF0000u);
      float f2 = __uint_as_float(u23 << 16), f3 = __uint_as_float(u23 & 0xFFFF0000u);
      s[nt]  += f0 + f1 + f2 + f3;
      s2[nt] += f0 * f0 + f1 * f1 + f2 * f2 + f3 * f3;
    }
  }
#pragma unroll
  for (int nt = 0; nt < 4; nt++) {
    float v = s[nt], v2 = s2[nt];
    v  += __shfl_xor(v, 16);  v  += __shfl_xor(v, 32);
    v2 += __shfl_xor(v2, 16); v2 += __shfl_xor(v2, 32);
    if (quad == 0) { red[0][w][nt][l15] = v; red[1][w][nt][l15] = v2; }
  }
  __syncthreads();
  if (t < 128) {
    int which = t >> 6, j = t & 63, nt = j >> 4, jl = j & 15;
    float v = red[which][0][nt][jl] + red[which][1][nt][jl] +
              red[which][2][nt][jl] + red[which][3][nt][jl];
    atomicAdd(&a.ws1f[(bi & 15) * 128 + t], v);  // t<64: sum[j], t>=64: sumsq[j]
  }
}

// ---------------------------------------------------------------------------
// D3: pass 2, pure streaming — NO GEMM. 256 blocks x 256 thr; each wave
// handles 2 (bi,w1) tasks of 16 slots. z1 = relu(a1*y1 + c1); y2 = z1@W2 + b2
// via xor-shuffle over the 16 j-lanes; y2 at true (b,q,s); BN2 partials.
// ---------------------------------------------------------------------------
__global__ __launch_bounds__(256) void k_p2(Args a)
{
  int p = blockIdx.x, t = threadIdx.x;
  int w = t >> 6, l = t & 63, l15 = l & 15, quad = l >> 4;
  __shared__ float sh_tot[128];
  __shared__ float sh_a1c1[128];
  __shared__ float rs[16], rs2[16];

  if (t < 128) {
    float accv = 0;
#pragma unroll
    for (int c = 0; c < 16; c++) accv += a.ws1f[c * 128 + t];
    sh_tot[t] = accv;
  }
  __syncthreads();
  if (t < 64) {
    float mean = sh_tot[t] * INV_N;
    float var = sh_tot[64 + t] * INV_N - mean * mean;
    float aa = a.g1[t] * rsqrtf(var + BN_EPS);
    sh_a1c1[t] = aa;
    sh_a1c1[64 + t] = a.bt1[t] - mean * aa;
  }
  __syncthreads();

  float a1v[4], c1v[4], w2v[4];
#pragma unroll
  for (int nt = 0; nt < 4; nt++) {
    int j = nt * 16 + l15;
    a1v[nt] = sh_a1c1[j]; c1v[nt] = sh_a1c1[64 + j]; w2v[nt] = a.W2[j];
  }
  float b2v = a.b2[0];
  float ls = 0, ls2 = 0;

#pragma unroll
  for (int task = 0; task < 2; task++) {
    int gw = (p * 4 + w) * 2 + task;      // 0..2047 = (bi, w1)
    int bi = gw >> 2, w1 = gw & 3;
    int b = bi >> 7, rem = bi & 127, qt = rem >> 3, st = rem & 7;
#pragma unroll
    for (int mt = 0; mt < 4; mt++) {
      float part[4] = {0, 0, 0, 0};
#pragma unroll
      for (int nt = 0; nt < 4; nt++) {
        int slot = (bi * 4 + w1) * 16 + mt * 4 + nt;
        uint2 v = *(const uint2*)(a.y1f + (size_t)(slot * 64 + l) * 4);
        float f0 = __uint_as_float(v.x << 16), f1 = __uint_as_float(v.x & 0xFFFF0000u);
        float f2 = __uint_as_float(v.y << 16), f3 = __uint_as_float(v.y & 0xFFFF0000u);
        part[0] += fmaxf(a1v[nt] * f0 + c1v[nt], 0.0f) * w2v[nt];
        part[1] += fmaxf(a1v[nt] * f1 + c1v[nt], 0.0f) * w2v[nt];
        part[2] += fmaxf(a1v[nt] * f2 + c1v[nt], 0.0f) * w2v[nt];
        part[3] += fmaxf(a1v[nt] * f3 + c1v[nt], 0.0f) * w2v[nt];
      }
#pragma unroll
      for (int r = 0; r < 4; r++) {
        float pv = part[r];
        pv += __shfl_xor(pv, 1); pv += __shfl_xor(pv, 2);
        pv += __shfl_xor(pv, 4); pv += __shfl_xor(pv, 8);
        part[r] = pv + b2v;
      }
      if (l15 == 0) {
        int q = qt * 16 + w1 * 4 + mt;
        int P = ((b * 256 + q) * 128) + st * 16 + quad * 4;
        f32x4 o;
#pragma unroll
        for (int r = 0; r < 4; r++) { o[r] = part[r]; ls += part[r]; ls2 += part[r] * part[r]; }
        *(f32x4*)(a.y2 + P) = o;
      }
    }
  }
  if (l15 == 0) { rs[t >> 4] = ls; rs2[t >> 4] = ls2; }
  __syncthreads();
  if (t == 0) {
    float sv = 0, sv2 = 0;
#pragma unroll
    for (int i = 0; i < 16; i++) { sv += rs[i]; sv2 += rs2[i]; }
    atomicAdd(&a.ws2f[(p & 15) * 2], sv);       // 16 adds/address
    atomicAdd(&a.ws2f[(p & 15) * 2 + 1], sv2);
  }
}

// ---------------------------------------------------------------------------
// D4: BN2 finalize (redundant, 32 floats) + out. 128 blocks, 4 floats/thread.
// ---------------------------------------------------------------------------
__global__ __launch_bounds__(256) void k_out(Args a)
{
  int t = threadIdx.x;
  float s = 0, s2 = 0;
#pragma unroll
  for (int c = 0; c < 16; c++) { s += a.ws2f[c * 2]; s2 += a.ws2f[c * 2 + 1]; }
  float mean = s * INV_N;
  float var = s2 * INV_N - mean * mean;
  float aa = a.g2[0] * rsqrtf(var + BN_EPS);
  float cc = a.bt2[0] - mean * aa;
  int i = (blockIdx.x * 256 + t) * 4;     // 128*256*4 = 131072 exactly
  f32x4 v = *(const f32x4*)(a.y2 + i);
  f32x4 o;
#pragma unroll
  for (int r = 0; r < 4; r++) o[r] = fmaxf(aa * v[r] + cc, 0.0f);
  *(f32x4*)(a.out + i) = o;
}

extern "C" void kernel_launch(void* const* d_in, const int* in_sizes, int n_in,
                              void* d_out, int out_size, void* d_ws, size_t ws_size,
                              hipStream_t stream)
{
  float* ws = (float*)d_ws;
  Args a;
  a.Sf  = (const float*)d_in[0];   // support [4,128,256]
  a.Qf  = (const float*)d_in[1];   // query   [4,256,256]
  a.W0  = (const float*)d_in[2];   // [256,512]
  a.b0  = (const float*)d_in[3];
  a.g0  = (const float*)d_in[4];
  a.bt0 = (const float*)d_in[5];
  a.W1  = (const float*)d_in[6];   // [64,256]
  a.b1  = (const float*)d_in[7];
  a.g1  = (const float*)d_in[8];
  a.bt1 = (const float*)d_in[9];
  a.W2  = (const float*)d_in[10];  // [1,64]
  a.b2  = (const float*)d_in[11];
  a.g2  = (const float*)d_in[12];
  a.bt2 = (const float*)d_in[13];

  a.Aq   = ws;                     // 262144 f
  a.As   = ws + 262144;            // 131072 f
  a.y2   = ws + 393216;            // 131072 f
  a.ws0s = ws + 524288;            // 96*512 = 49152 f (BN0 slots, fully overwritten)
  a.ws1f = ws + 573440;            // 2048 f (16-way spread atomics, zeroed by D1 blk96)
  a.ws2f = ws + 575488;            // 32 f   (16-way spread atomics, zeroed by D1 blk96)
  a.W1h  = (ushort*)(ws + 575552); // 16384 u16 = 8192 f
  a.W1l  = (ushort*)(ws + 583744); // 16384 u16
  a.y1f  = (ushort*)(ws + 591936); // 8388608 u16 = 16 MB (y1 frags)
  a.out  = (float*)d_out;          // total ws use ~18.6 MB

  k_g0 <<<97, 256, 0, stream>>>(a);
  k_m1 <<<512, 256, 0, stream>>>(a);
  k_p2 <<<256, 256, 0, stream>>>(a);
  k_out<<<128, 256, 0, stream>>>(a);
}

// Round 14
// 131.956 us; speedup vs baseline: 1.4633x; 1.0428x over previous
//
#include <hip/hip_runtime.h>
#include <hip/hip_bf16.h>

// RelationNet fused pipeline, fp32 in/out — FOUR dispatches, no grid barriers.
// B=4 Q=256 S=128 C=256; feats 512 -> 256 -> 64 -> 1; BN (training) + ReLU each layer.
//
// Factorization: concat(uq,us)@W0^T = query@W0a^T + support@W0b^T => Aq[b,q,o], As[b,s,o]
// (b0 folded into As). BN0 stats analytic from per-b sums.
// GEMM0 ~fp32 via 3-term in-register hi/lo bf16 split (inputs fp32-exactness matters
// for BN0 stats). GEMM1: z-side bf16-RNE, W1-side plain bf16-RNE (R14: dropped the
// hi/lo split — z's 2^-9 already dominates; halves MFMA + LDS).
// y1 stored bf16 frag-order (16 MB); pass 2 is pure streaming; BN1/BN2 partials via
// spread atomicAdd; BN finalizes redundant per block (R5-R9: grid barriers ~30us/phase,
// kernel boundaries cheaper; R13: per-dispatch floor ~20-35us, work-insensitive).

typedef __attribute__((ext_vector_type(4))) float f32x4;
typedef __attribute__((ext_vector_type(8))) short s16x8;

#define BN_EPS 1e-5f
#define INV_N  (1.0f/131072.0f)

__device__ __forceinline__ unsigned pk_bf16(float a, float b) {
  float2 t; t.x = a; t.y = b;
  __hip_bfloat162 h = __float22bfloat162_rn(t);
  return *reinterpret_cast<unsigned*>(&h);  // low16 = bf16(a), high16 = bf16(b)
}
__device__ __forceinline__ void split2(float a, float b, unsigned& uh, unsigned& ul) {
  uh = pk_bf16(a, b);
  float ha = __uint_as_float(uh << 16);
  float hb = __uint_as_float(uh & 0xFFFF0000u);
  ul = pk_bf16(a - ha, b - hb);
}

union frag_u { s16x8 v; unsigned u[4]; };

struct Args {
  const float *Sf, *Qf, *W0, *b0, *g0, *bt0, *W1, *b1, *g1, *bt1, *W2, *b2, *g2, *bt2;
  float *Aq, *As, *y2, *ws0s, *ws1f, *ws2f, *out;
  ushort *y1f;
};

// ---------------------------------------------------------------------------
// D1: GEMM0. 385 blocks x 64 thr (one 16x64 wave-tile each — R14: spread over
// all 256 CUs; 96x256 left 160 CUs idle). chunk = bi>>2 (0..63 Aq, 64..95 As),
// ntile = bi&3. W0 split in-register (3-term). BN0 partial slots (no atomics):
// ws0s[chunk*512 + o] / [..+256+o] = sum/sumsq over the chunk's 16 rows.
// Block 384: zero ws1f/ws2f atomic pads.
// ---------------------------------------------------------------------------
__global__ __launch_bounds__(64) void k_g0(Args a)
{
  int bi = blockIdx.x, t = threadIdx.x;
  if (bi == 384) {
    for (int i = t; i < 2048; i += 64) a.ws1f[i] = 0.0f;
    if (t < 32) a.ws2f[t] = 0.0f;
    return;
  }
  int l15 = t & 15, quad = t >> 4;
  int chunk = bi >> 2, ntile = bi & 3;
  bool isQ = (chunk < 64);
  const float* X; float* Out; int m0, koff;
  if (isQ) { m0 = chunk * 16; X = a.Qf; Out = a.Aq; koff = 0; }
  else     { m0 = (chunk - 64) * 16; X = a.Sf; Out = a.As; koff = 256; }
  int n0 = ntile * 64;

  f32x4 acc[4] = {};
#pragma unroll
  for (int ko = 0; ko < 256; ko += 32) {
    const float* row = X + (m0 + l15) * 256 + ko + quad * 8;
    f32x4 v0 = *(const f32x4*)(row);
    f32x4 v1 = *(const f32x4*)(row + 4);
    frag_u ah, al;
#pragma unroll
    for (int j = 0; j < 2; j++) {
      split2(v0[2 * j], v0[2 * j + 1], ah.u[j], al.u[j]);
      split2(v1[2 * j], v1[2 * j + 1], ah.u[2 + j], al.u[2 + j]);
    }
#pragma unroll
    for (int nt = 0; nt < 4; nt++) {
      const float* wrow = a.W0 + (n0 + nt * 16 + l15) * 512 + koff + ko + quad * 8;
      f32x4 w0v = *(const f32x4*)(wrow);
      f32x4 w1v = *(const f32x4*)(wrow + 4);
      frag_u bh, bl;
      split2(w0v[0], w0v[1], bh.u[0], bl.u[0]);
      split2(w0v[2], w0v[3], bh.u[1], bl.u[1]);
      split2(w1v[0], w1v[1], bh.u[2], bl.u[2]);
      split2(w1v[2], w1v[3], bh.u[3], bl.u[3]);
      acc[nt] = __builtin_amdgcn_mfma_f32_16x16x32_bf16(ah.v, bh.v, acc[nt], 0, 0, 0);
      acc[nt] = __builtin_amdgcn_mfma_f32_16x16x32_bf16(al.v, bh.v, acc[nt], 0, 0, 0);
      acc[nt] = __builtin_amdgcn_mfma_f32_16x16x32_bf16(ah.v, bl.v, acc[nt], 0, 0, 0);
    }
  }
  // D: col = l15 (o-in-tile), row = quad*4 + r
#pragma unroll
  for (int nt = 0; nt < 4; nt++) {
    int o = n0 + nt * 16 + l15;
    float bias = isQ ? 0.0f : a.b0[o];
    float cs = 0, cs2 = 0;
#pragma unroll
    for (int r = 0; r < 4; r++) {
      float y = acc[nt][r] + bias;
      Out[(m0 + quad * 4 + r) * 256 + o] = y;
      cs += y; cs2 += y * y;
    }
    cs  += __shfl_xor(cs, 16);  cs  += __shfl_xor(cs, 32);
    cs2 += __shfl_xor(cs2, 16); cs2 += __shfl_xor(cs2, 32);
    if (quad == 0) {
      a.ws0s[chunk * 512 + o] = cs;
      a.ws0s[chunk * 512 + 256 + o] = cs2;
    }
  }
}

// Redundant per-block BN0 finalize from D1's slots -> LDS a0/c0.
__device__ __forceinline__ void bn0_finalize(const Args& a, int t, float* sh_a0c0)
{
  int o = t;
  float sumY = 0, cross = 0, SQ2 = 0, SS2 = 0;
#pragma unroll
  for (int b = 0; b < 4; b++) {
    float sq1 = 0, sq2 = 0, ss1 = 0, ss2 = 0;
#pragma unroll
    for (int c = 0; c < 16; c++) {
      sq1 += a.ws0s[(b * 16 + c) * 512 + o];
      sq2 += a.ws0s[(b * 16 + c) * 512 + 256 + o];
    }
#pragma unroll
    for (int c = 0; c < 8; c++) {
      ss1 += a.ws0s[(64 + b * 8 + c) * 512 + o];
      ss2 += a.ws0s[(64 + b * 8 + c) * 512 + 256 + o];
    }
    SQ2 += sq2; SS2 += ss2;
    sumY += 128.0f * sq1 + 256.0f * ss1;
    cross += sq1 * ss1;
  }
  float mean = sumY * INV_N;
  float var = (128.0f * SQ2 + 256.0f * SS2 + 2.0f * cross) * INV_N - mean * mean;
  float aa = a.g0[o] * rsqrtf(var + BN_EPS);
  sh_a0c0[o] = aa;
  sh_a0c0[256 + o] = a.bt0[o] - mean * aa;
}

// ---------------------------------------------------------------------------
// D2: main GEMM. 512 blocks, one (b,qt,st) tile each. z0 bf16-RNE in regs;
// W1 plain bf16-RNE staged fp32->LDS in FRAGMENT ORDER (frag fr=(kk*4+nt)*64+l
// -> 8 shorts at w1f+fr*8, lane-contiguous 16B, conflict-free). 16 MFMA/kk.
// y1 (bias-added, bf16-RNE) stored to global frag layout:
// y1f[slot*256 + l*4 + r], slot = (bi*4+w)*16 + mt*4 + nt.
// BN1 stats from the STORED bf16 values -> 16-way-spread atomicAdd ws1f.
// ---------------------------------------------------------------------------
__global__ __launch_bounds__(256) void k_m1(Args a)
{
  int bi = blockIdx.x, t = threadIdx.x;
  int w = t >> 6, l = t & 63, l15 = l & 15, quad = l >> 4;
  __shared__ ushort w1f[2048 * 8];    // 32 KB, frag order
  __shared__ float sh_a0c0[512];
  __shared__ float red[2][4][4][16];

  // stage W1 (fp32) -> LDS bf16 frag order
#pragma unroll
  for (int i = 0; i < 8; i++) {
    int fr = i * 256 + t;
    int kk = fr >> 8, r = fr & 255, nt = r >> 6, ln = r & 63;
    const float* src = a.W1 + (nt * 16 + (ln & 15)) * 256 + kk * 32 + (ln >> 4) * 8;
    f32x4 v0 = *(const f32x4*)(src);
    f32x4 v1 = *(const f32x4*)(src + 4);
    frag_u z;
    z.u[0] = pk_bf16(v0[0], v0[1]); z.u[1] = pk_bf16(v0[2], v0[3]);
    z.u[2] = pk_bf16(v1[0], v1[1]); z.u[3] = pk_bf16(v1[2], v1[3]);
    *(s16x8*)(w1f + fr * 8) = z.v;
  }
  bn0_finalize(a, t, sh_a0c0);
  __syncthreads();

  int b_ = bi >> 7, rem = bi & 127, qt = rem >> 3, st = rem & 7;
  const float* asrow = a.As + ((b_ << 7) + st * 16 + l15) * 256;
  const float* aqrow[4];
#pragma unroll
  for (int mt = 0; mt < 4; mt++)
    aqrow[mt] = a.Aq + ((b_ << 8) + qt * 16 + w * 4 + mt) * 256;

  f32x4 acc[4][4] = {};
#pragma unroll
  for (int kk = 0; kk < 8; kk++) {
    int obase = kk * 32 + quad * 8;
    f32x4 a0v0 = *(const f32x4*)(sh_a0c0 + obase);
    f32x4 a0v1 = *(const f32x4*)(sh_a0c0 + obase + 4);
    f32x4 c0v0 = *(const f32x4*)(sh_a0c0 + 256 + obase);
    f32x4 c0v1 = *(const f32x4*)(sh_a0c0 + 256 + obase + 4);
    f32x4 as0 = *(const f32x4*)(asrow + obase);
    f32x4 as1 = *(const f32x4*)(asrow + obase + 4);

    s16x8 zh[4];
#pragma unroll
    for (int mt = 0; mt < 4; mt++) {
      f32x4 aq0 = *(const f32x4*)(aqrow[mt] + obase);
      f32x4 aq1 = *(const f32x4*)(aqrow[mt] + obase + 4);
      f32x4 z0 = (aq0 + as0) * a0v0 + c0v0;
      f32x4 z1 = (aq1 + as1) * a0v1 + c0v1;
      frag_u zz;
      zz.u[0] = pk_bf16(fmaxf(z0[0], 0.0f), fmaxf(z0[1], 0.0f));
      zz.u[1] = pk_bf16(fmaxf(z0[2], 0.0f), fmaxf(z0[3], 0.0f));
      zz.u[2] = pk_bf16(fmaxf(z1[0], 0.0f), fmaxf(z1[1], 0.0f));
      zz.u[3] = pk_bf16(fmaxf(z1[2], 0.0f), fmaxf(z1[3], 0.0f));
      zh[mt] = zz.v;
    }
#pragma unroll
    for (int nt = 0; nt < 4; nt++) {
      s16x8 bw = *(const s16x8*)(w1f + ((kk * 4 + nt) * 64 + l) * 8);
#pragma unroll
      for (int mt = 0; mt < 4; mt++)
        acc[mt][nt] = __builtin_amdgcn_mfma_f32_16x16x32_bf16(zh[mt], bw, acc[mt][nt], 0, 0, 0);
    }
  }

  // epilogue: add bias, bf16-round, store y1 frags, stats from stored values
  float biasv[4];
#pragma unroll
  for (int nt = 0; nt < 4; nt++) biasv[nt] = a.b1[nt * 16 + l15];
  float s[4] = {0, 0, 0, 0}, s2[4] = {0, 0, 0, 0};
#pragma unroll
  for (int mt = 0; mt < 4; mt++) {
#pragma unroll
    for (int nt = 0; nt < 4; nt++) {
      float y0 = acc[mt][nt][0] + biasv[nt];
      float y1 = acc[mt][nt][1] + biasv[nt];
      float y2v = acc[mt][nt][2] + biasv[nt];
      float y3 = acc[mt][nt][3] + biasv[nt];
      unsigned u01 = pk_bf16(y0, y1), u23 = pk_bf16(y2v, y3);
      uint2 pk; pk.x = u01; pk.y = u23;
      int slot = (bi * 4 + w) * 16 + mt * 4 + nt;
      *(uint2*)(a.y1f + (size_t)(slot * 64 + l) * 4) = pk;
      float f0 = __uint_as_float(u01 << 16), f1 = __uint_as_float(u01 & 0xFFFF0000u);
      float f2 = __uint_as_float(u23 << 16), f3 = __uint_as_float(u23 & 0xFFFF0000u);
      s[nt]  += f0 + f1 + f2 + f3;
      s2[nt] += f0 * f0 + f1 * f1 + f2 * f2 + f3 * f3;
    }
  }
#pragma unroll
  for (int nt = 0; nt < 4; nt++) {
    float v = s[nt], v2 = s2[nt];
    v  += __shfl_xor(v, 16);  v  += __shfl_xor(v, 32);
    v2 += __shfl_xor(v2, 16); v2 += __shfl_xor(v2, 32);
    if (quad == 0) { red[0][w][nt][l15] = v; red[1][w][nt][l15] = v2; }
  }
  __syncthreads();
  if (t < 128) {
    int which = t >> 6, j = t & 63, nt = j >> 4, jl = j & 15;
    float v = red[which][0][nt][jl] + red[which][1][nt][jl] +
              red[which][2][nt][jl] + red[which][3][nt][jl];
    atomicAdd(&a.ws1f[(bi & 15) * 128 + t], v);  // t<64: sum[j], t>=64: sumsq[j]
  }
}

// ---------------------------------------------------------------------------
// D3: pass 2, pure streaming — NO GEMM. 256 blocks x 256 thr; each wave
// handles 2 (bi,w1) tasks of 16 slots. z1 = relu(a1*y1 + c1); y2 = z1@W2 + b2
// via xor-shuffle over the 16 j-lanes; y2 at true (b,q,s); BN2 partials.
// ---------------------------------------------------------------------------
__global__ __launch_bounds__(256) void k_p2(Args a)
{
  int p = blockIdx.x, t = threadIdx.x;
  int w = t >> 6, l = t & 63, l15 = l & 15, quad = l >> 4;
  __shared__ float sh_tot[128];
  __shared__ float sh_a1c1[128];
  __shared__ float rs[16], rs2[16];

  if (t < 128) {
    float accv = 0;
#pragma unroll
    for (int c = 0; c < 16; c++) accv += a.ws1f[c * 128 + t];
    sh_tot[t] = accv;
  }
  __syncthreads();
  if (t < 64) {
    float mean = sh_tot[t] * INV_N;
    float var = sh_tot[64 + t] * INV_N - mean * mean;
    float aa = a.g1[t] * rsqrtf(var + BN_EPS);
    sh_a1c1[t] = aa;
    sh_a1c1[64 + t] = a.bt1[t] - mean * aa;
  }
  __syncthreads();

  float a1v[4], c1v[4], w2v[4];
#pragma unroll
  for (int nt = 0; nt < 4; nt++) {
    int j = nt * 16 + l15;
    a1v[nt] = sh_a1c1[j]; c1v[nt] = sh_a1c1[64 + j]; w2v[nt] = a.W2[j];
  }
  float b2v = a.b2[0];
  float ls = 0, ls2 = 0;

#pragma unroll
  for (int task = 0; task < 2; task++) {
    int gw = (p * 4 + w) * 2 + task;      // 0..2047 = (bi, w1)
    int bi = gw >> 2, w1 = gw & 3;
    int b = bi >> 7, rem = bi & 127, qt = rem >> 3, st = rem & 7;
#pragma unroll
    for (int mt = 0; mt < 4; mt++) {
      float part[4] = {0, 0, 0, 0};
#pragma unroll
      for (int nt = 0; nt < 4; nt++) {
        int slot = (bi * 4 + w1) * 16 + mt * 4 + nt;
        uint2 v = *(const uint2*)(a.y1f + (size_t)(slot * 64 + l) * 4);
        float f0 = __uint_as_float(v.x << 16), f1 = __uint_as_float(v.x & 0xFFFF0000u);
        float f2 = __uint_as_float(v.y << 16), f3 = __uint_as_float(v.y & 0xFFFF0000u);
        part[0] += fmaxf(a1v[nt] * f0 + c1v[nt], 0.0f) * w2v[nt];
        part[1] += fmaxf(a1v[nt] * f1 + c1v[nt], 0.0f) * w2v[nt];
        part[2] += fmaxf(a1v[nt] * f2 + c1v[nt], 0.0f) * w2v[nt];
        part[3] += fmaxf(a1v[nt] * f3 + c1v[nt], 0.0f) * w2v[nt];
      }
#pragma unroll
      for (int r = 0; r < 4; r++) {
        float pv = part[r];
        pv += __shfl_xor(pv, 1); pv += __shfl_xor(pv, 2);
        pv += __shfl_xor(pv, 4); pv += __shfl_xor(pv, 8);
        part[r] = pv + b2v;
      }
      if (l15 == 0) {
        int q = qt * 16 + w1 * 4 + mt;
        int P = ((b * 256 + q) * 128) + st * 16 + quad * 4;
        f32x4 o;
#pragma unroll
        for (int r = 0; r < 4; r++) { o[r] = part[r]; ls += part[r]; ls2 += part[r] * part[r]; }
        *(f32x4*)(a.y2 + P) = o;
      }
    }
  }
  if (l15 == 0) { rs[t >> 4] = ls; rs2[t >> 4] = ls2; }
  __syncthreads();
  if (t == 0) {
    float sv = 0, sv2 = 0;
#pragma unroll
    for (int i = 0; i < 16; i++) { sv += rs[i]; sv2 += rs2[i]; }
    atomicAdd(&a.ws2f[(p & 15) * 2], sv);       // 16 adds/address
    atomicAdd(&a.ws2f[(p & 15) * 2 + 1], sv2);
  }
}

// ---------------------------------------------------------------------------
// D4: BN2 finalize (redundant, 32 floats) + out. 128 blocks, 4 floats/thread.
// ---------------------------------------------------------------------------
__global__ __launch_bounds__(256) void k_out(Args a)
{
  int t = threadIdx.x;
  float s = 0, s2 = 0;
#pragma unroll
  for (int c = 0; c < 16; c++) { s += a.ws2f[c * 2]; s2 += a.ws2f[c * 2 + 1]; }
  float mean = s * INV_N;
  float var = s2 * INV_N - mean * mean;
  float aa = a.g2[0] * rsqrtf(var + BN_EPS);
  float cc = a.bt2[0] - mean * aa;
  int i = (blockIdx.x * 256 + t) * 4;     // 128*256*4 = 131072 exactly
  f32x4 v = *(const f32x4*)(a.y2 + i);
  f32x4 o;
#pragma unroll
  for (int r = 0; r < 4; r++) o[r] = fmaxf(aa * v[r] + cc, 0.0f);
  *(f32x4*)(a.out + i) = o;
}

extern "C" void kernel_launch(void* const* d_in, const int* in_sizes, int n_in,
                              void* d_out, int out_size, void* d_ws, size_t ws_size,
                              hipStream_t stream)
{
  float* ws = (float*)d_ws;
  Args a;
  a.Sf  = (const float*)d_in[0];   // support [4,128,256]
  a.Qf  = (const float*)d_in[1];   // query   [4,256,256]
  a.W0  = (const float*)d_in[2];   // [256,512]
  a.b0  = (const float*)d_in[3];
  a.g0  = (const float*)d_in[4];
  a.bt0 = (const float*)d_in[5];
  a.W1  = (const float*)d_in[6];   // [64,256]
  a.b1  = (const float*)d_in[7];
  a.g1  = (const float*)d_in[8];
  a.bt1 = (const float*)d_in[9];
  a.W2  = (const float*)d_in[10];  // [1,64]
  a.b2  = (const float*)d_in[11];
  a.g2  = (const float*)d_in[12];
  a.bt2 = (const float*)d_in[13];

  a.Aq   = ws;                     // 262144 f
  a.As   = ws + 262144;            // 131072 f
  a.y2   = ws + 393216;            // 131072 f
  a.ws0s = ws + 524288;            // 96*512 = 49152 f (BN0 slots, fully overwritten)
  a.ws1f = ws + 573440;            // 2048 f (16-way spread atomics, zeroed by D1 blk384)
  a.ws2f = ws + 575488;            // 32 f   (16-way spread atomics, zeroed by D1 blk384)
  a.y1f  = (ushort*)(ws + 575552); // 8388608 u16 = 16 MB (y1 frags)
  a.out  = (float*)d_out;          // total ws use ~18.6 MB

  k_g0 <<<385, 64, 0, stream>>>(a);
  k_m1 <<<512, 256, 0, stream>>>(a);
  k_p2 <<<256, 256, 0, stream>>>(a);
  k_out<<<128, 256, 0, stream>>>(a);
}